// Round 1
// baseline (4766.431 us; speedup 1.0000x reference)
//
#include <hip/hip_runtime.h>
#include <math.h>

#define N_TOK 8192
#define DIM 2048
#define HDIM 2048
#define ODIM 2048
#define NEXP 8
#define CAPACITY 2560

#define TM 64
#define TN 64
#define BK 16

// ---------------- router: 1 wave per token ----------------
__global__ __launch_bounds__(64) void router_kernel(
    const float* __restrict__ x, const float* __restrict__ gate_w,
    const float* __restrict__ gate_b, const float* __restrict__ temp,
    float* __restrict__ probs, int* __restrict__ sel, float* __restrict__ rwv) {
  int t = blockIdx.x;
  int lane = threadIdx.x;
  const float* xr = x + (size_t)t * DIM;
  float part[NEXP];
#pragma unroll
  for (int e = 0; e < NEXP; e++) part[e] = 0.f;
  for (int k = lane; k < DIM; k += 64) {
    float xv = xr[k];
    const float* gw = gate_w + (size_t)k * NEXP;
#pragma unroll
    for (int e = 0; e < NEXP; e++) part[e] += xv * gw[e];
  }
#pragma unroll
  for (int e = 0; e < NEXP; e++) {
    float v = part[e];
#pragma unroll
    for (int off = 32; off > 0; off >>= 1) v += __shfl_down(v, off);
    part[e] = v;
  }
  if (lane == 0) {
    float it = 1.0f / fabsf(temp[0]);
    float lg[NEXP];
    float m = -1e30f;
#pragma unroll
    for (int e = 0; e < NEXP; e++) {
      lg[e] = (part[e] + gate_b[e]) * it;
      m = fmaxf(m, lg[e]);
    }
    float s = 0.f;
    float p[NEXP];
#pragma unroll
    for (int e = 0; e < NEXP; e++) { p[e] = expf(lg[e] - m); s += p[e]; }
    float inv_s = 1.f / s;
#pragma unroll
    for (int e = 0; e < NEXP; e++) { p[e] *= inv_s; probs[(size_t)t * NEXP + e] = p[e]; }
    // top-2, ties -> lowest index (matches jax.lax.top_k)
    int e1 = 0;
#pragma unroll
    for (int e = 1; e < NEXP; e++) if (p[e] > p[e1]) e1 = e;
    int e2 = -1;
#pragma unroll
    for (int e = 0; e < NEXP; e++) {
      if (e == e1) continue;
      if (e2 < 0 || p[e] > p[e2]) e2 = e;
    }
    float s2 = p[e1] + p[e2];
    sel[t * 2 + 0] = e1;
    sel[t * 2 + 1] = e2;
    rwv[t * 2 + 0] = p[e1] / s2;
    rwv[t * 2 + 1] = p[e2] / s2;
  }
}

// ---------------- aux loss + per-expert assignment counts ----------------
__global__ __launch_bounds__(256) void aux_kernel(
    const float* __restrict__ probs, const int* __restrict__ sel,
    float* __restrict__ aux_out, int* __restrict__ cnt_assign,
    int* __restrict__ list_cnt) {
  int tid = threadIdx.x;
  float lps[NEXP];
  int lc[NEXP];
#pragma unroll
  for (int e = 0; e < NEXP; e++) { lps[e] = 0.f; lc[e] = 0; }
  for (int t = tid; t < N_TOK; t += 256) {
    const float* pr = probs + (size_t)t * NEXP;
#pragma unroll
    for (int e = 0; e < NEXP; e++) lps[e] += pr[e];
  }
  for (int j = tid; j < N_TOK * 2; j += 256) lc[sel[j]]++;
  __shared__ float sps[NEXP][256];
  __shared__ int scs[NEXP][256];
#pragma unroll
  for (int e = 0; e < NEXP; e++) { sps[e][tid] = lps[e]; scs[e][tid] = lc[e]; }
  __syncthreads();
  for (int off = 128; off > 0; off >>= 1) {
    if (tid < off) {
#pragma unroll
      for (int e = 0; e < NEXP; e++) {
        sps[e][tid] += sps[e][tid + off];
        scs[e][tid] += scs[e][tid + off];
      }
    }
    __syncthreads();
  }
  if (tid < NEXP) {
    cnt_assign[tid] = scs[tid][0];
    list_cnt[tid] = 0;
  }
  if (tid == 0) {
    float ps[NEXP];
    int cs[NEXP];
#pragma unroll
    for (int e = 0; e < NEXP; e++) { ps[e] = sps[e][0]; cs[e] = scs[e][0]; }
    float balance = 0.f;
#pragma unroll
    for (int e = 0; e < NEXP; e++)
      balance += (ps[e] / (float)N_TOK) * ((float)cs[e] / (float)N_TOK);
    balance *= (float)NEXP;
    float meanimp = 0.f;
#pragma unroll
    for (int e = 0; e < NEXP; e++) meanimp += ps[e];
    meanimp /= (float)NEXP;
    float var = 0.f;
#pragma unroll
    for (int e = 0; e < NEXP; e++) { float d = ps[e] - meanimp; var += d * d; }
    var /= (float)(NEXP - 1);
    float cv = sqrtf(var) / (meanimp + 1e-10f);
    aux_out[0] = balance + 0.01f * cv;
  }
}

// ---------------- out = x (residual init) ----------------
__global__ __launch_bounds__(256) void copy_kernel(const float4* __restrict__ src,
                                                   float4* __restrict__ dst, int n4) {
  int i = blockIdx.x * blockDim.x + threadIdx.x;
  int stride = gridDim.x * blockDim.x;
  for (; i < n4; i += stride) dst[i] = src[i];
}

// ---------------- capacity-exact expert list build ----------------
__global__ __launch_bounds__(256) void build_lists(
    const int* __restrict__ sel, const float* __restrict__ rwv,
    const int* __restrict__ cnt_assign, int* __restrict__ list_cnt,
    int* __restrict__ etok, float* __restrict__ ewt) {
  int j = blockIdx.x * blockDim.x + threadIdx.x;
  if (j >= N_TOK * 2) return;
  int e = sel[j];
  float w = rwv[j];
  bool keep = true;
  if (cnt_assign[e] > CAPACITY) {
    // exact rank matching top_k over flattened [n*K] with sentinel -1:
    // value desc, tie -> lower flat index
    int rank = 0;
    for (int j2 = 0; j2 < N_TOK * 2; j2++) {
      if (sel[j2] == e) {
        float w2 = rwv[j2];
        if (w2 > w || (w2 == w && j2 < j)) rank++;
      }
    }
    keep = (rank < CAPACITY);
  }
  if (keep) {
    int slot = atomicAdd(&list_cnt[e], 1);
    etok[(size_t)e * CAPACITY + slot] = j >> 1;  // token index (K=2)
    ewt[(size_t)e * CAPACITY + slot] = w;
  }
}

// ---------------- FFN1: h = relu(X[tok] @ w1 + b1) ----------------
__global__ __launch_bounds__(256) void ffn1_kernel(
    const float* __restrict__ x, const float* __restrict__ w1,
    const float* __restrict__ b1, const int* __restrict__ etok,
    const int* __restrict__ ecnt, float* __restrict__ h) {
  int cnt = *ecnt;
  int row0 = blockIdx.x * TM;
  if (row0 >= cnt) return;
  int col0 = blockIdx.y * TN;
  __shared__ float As[BK][TM + 4];  // [k][m]
  __shared__ float Bs[BK][TN + 4];  // [k][n]
  int tid = threadIdx.x;
  int tx = tid & 15, ty = tid >> 4;
  int arow = tid >> 2;
  int ak = (tid & 3) * 4;
  const float* xrow = nullptr;
  if (row0 + arow < cnt) xrow = x + (size_t)etok[row0 + arow] * DIM;
  int bk = tid >> 4;
  int bc = (tid & 15) * 4;
  float acc[4][4];
#pragma unroll
  for (int i = 0; i < 4; i++)
#pragma unroll
    for (int jj = 0; jj < 4; jj++) acc[i][jj] = 0.f;

  for (int k0 = 0; k0 < DIM; k0 += BK) {
    float4 av = make_float4(0.f, 0.f, 0.f, 0.f);
    if (xrow) av = *(const float4*)(xrow + k0 + ak);
    As[ak + 0][arow] = av.x;
    As[ak + 1][arow] = av.y;
    As[ak + 2][arow] = av.z;
    As[ak + 3][arow] = av.w;
    float4 bv = *(const float4*)(w1 + (size_t)(k0 + bk) * HDIM + col0 + bc);
    *(float4*)&Bs[bk][bc] = bv;
    __syncthreads();
#pragma unroll
    for (int kk = 0; kk < BK; kk++) {
      float4 a = *(const float4*)&As[kk][ty * 4];
      float4 b = *(const float4*)&Bs[kk][tx * 4];
      acc[0][0] += a.x * b.x; acc[0][1] += a.x * b.y; acc[0][2] += a.x * b.z; acc[0][3] += a.x * b.w;
      acc[1][0] += a.y * b.x; acc[1][1] += a.y * b.y; acc[1][2] += a.y * b.z; acc[1][3] += a.y * b.w;
      acc[2][0] += a.z * b.x; acc[2][1] += a.z * b.y; acc[2][2] += a.z * b.z; acc[2][3] += a.z * b.w;
      acc[3][0] += a.w * b.x; acc[3][1] += a.w * b.y; acc[3][2] += a.w * b.z; acc[3][3] += a.w * b.w;
    }
    __syncthreads();
  }
#pragma unroll
  for (int i = 0; i < 4; i++) {
    int r = row0 + ty * 4 + i;
    if (r < cnt) {
      int c = col0 + tx * 4;
      float4 o;
      o.x = fmaxf(acc[i][0] + b1[c + 0], 0.f);
      o.y = fmaxf(acc[i][1] + b1[c + 1], 0.f);
      o.z = fmaxf(acc[i][2] + b1[c + 2], 0.f);
      o.w = fmaxf(acc[i][3] + b1[c + 3], 0.f);
      *(float4*)(h + (size_t)r * HDIM + c) = o;
    }
  }
}

// ---------------- FFN2: out[tok] += (h @ w2 + b2) * w ----------------
__global__ __launch_bounds__(256) void ffn2_kernel(
    const float* __restrict__ h, const float* __restrict__ w2,
    const float* __restrict__ b2, const int* __restrict__ etok,
    const float* __restrict__ ewt, const int* __restrict__ ecnt,
    float* __restrict__ out) {
  int cnt = *ecnt;
  int row0 = blockIdx.x * TM;
  if (row0 >= cnt) return;
  int col0 = blockIdx.y * TN;
  __shared__ float As[BK][TM + 4];
  __shared__ float Bs[BK][TN + 4];
  int tid = threadIdx.x;
  int tx = tid & 15, ty = tid >> 4;
  int arow = tid >> 2;
  int ak = (tid & 3) * 4;
  bool a_ok = (row0 + arow < cnt);
  const float* hrow = h + (size_t)(row0 + arow) * HDIM;
  int bk = tid >> 4;
  int bc = (tid & 15) * 4;
  float acc[4][4];
#pragma unroll
  for (int i = 0; i < 4; i++)
#pragma unroll
    for (int jj = 0; jj < 4; jj++) acc[i][jj] = 0.f;

  for (int k0 = 0; k0 < HDIM; k0 += BK) {
    float4 av = make_float4(0.f, 0.f, 0.f, 0.f);
    if (a_ok) av = *(const float4*)(hrow + k0 + ak);
    As[ak + 0][arow] = av.x;
    As[ak + 1][arow] = av.y;
    As[ak + 2][arow] = av.z;
    As[ak + 3][arow] = av.w;
    float4 bv = *(const float4*)(w2 + (size_t)(k0 + bk) * ODIM + col0 + bc);
    *(float4*)&Bs[bk][bc] = bv;
    __syncthreads();
#pragma unroll
    for (int kk = 0; kk < BK; kk++) {
      float4 a = *(const float4*)&As[kk][ty * 4];
      float4 b = *(const float4*)&Bs[kk][tx * 4];
      acc[0][0] += a.x * b.x; acc[0][1] += a.x * b.y; acc[0][2] += a.x * b.z; acc[0][3] += a.x * b.w;
      acc[1][0] += a.y * b.x; acc[1][1] += a.y * b.y; acc[1][2] += a.y * b.z; acc[1][3] += a.y * b.w;
      acc[2][0] += a.z * b.x; acc[2][1] += a.z * b.y; acc[2][2] += a.z * b.z; acc[2][3] += a.z * b.w;
      acc[3][0] += a.w * b.x; acc[3][1] += a.w * b.y; acc[3][2] += a.w * b.z; acc[3][3] += a.w * b.w;
    }
    __syncthreads();
  }
#pragma unroll
  for (int i = 0; i < 4; i++) {
    int r = row0 + ty * 4 + i;
    if (r < cnt) {
      int tok = etok[r];
      float wt = ewt[r];
      int c = col0 + tx * 4;
      float* orow = out + (size_t)tok * ODIM;
#pragma unroll
      for (int jj = 0; jj < 4; jj++)
        atomicAdd(&orow[c + jj], (acc[i][jj] + b2[c + jj]) * wt);
    }
  }
}

extern "C" void kernel_launch(void* const* d_in, const int* in_sizes, int n_in,
                              void* d_out, int out_size, void* d_ws, size_t ws_size,
                              hipStream_t stream) {
  const float* x = (const float*)d_in[0];
  const float* gate_w = (const float*)d_in[1];
  const float* gate_b = (const float*)d_in[2];
  const float* temp = (const float*)d_in[3];
  const float* w1 = (const float*)d_in[4];
  const float* b1 = (const float*)d_in[5];
  const float* w2 = (const float*)d_in[6];
  const float* b2 = (const float*)d_in[7];
  float* out = (float*)d_out;

  char* ws = (char*)d_ws;
  size_t off = 0;
  float* probs = (float*)(ws + off); off += (size_t)N_TOK * NEXP * 4;        // 262144
  int* sel = (int*)(ws + off);       off += (size_t)N_TOK * 2 * 4;           // 65536
  float* rwv = (float*)(ws + off);   off += (size_t)N_TOK * 2 * 4;           // 65536
  int* cnt_assign = (int*)(ws + off); off += 64;
  int* list_cnt = (int*)(ws + off);   off += 64;
  int* etok = (int*)(ws + off);      off += (size_t)NEXP * CAPACITY * 4;     // 81920
  float* ewt = (float*)(ws + off);   off += (size_t)NEXP * CAPACITY * 4;     // 81920
  off = (off + 255) & ~(size_t)255;
  float* hbuf = (float*)(ws + off);  // CAPACITY * HDIM * 4 = 21 MB (reused per expert)

  router_kernel<<<N_TOK, 64, 0, stream>>>(x, gate_w, gate_b, temp, probs, sel, rwv);
  float* aux_out = out + (size_t)N_TOK * ODIM;
  aux_kernel<<<1, 256, 0, stream>>>(probs, sel, aux_out, cnt_assign, list_cnt);
  int n4 = (N_TOK * ODIM) / 4;
  copy_kernel<<<4096, 256, 0, stream>>>((const float4*)x, (float4*)out, n4);
  build_lists<<<(N_TOK * 2 + 255) / 256, 256, 0, stream>>>(sel, rwv, cnt_assign,
                                                           list_cnt, etok, ewt);
  dim3 gemm_grid(CAPACITY / TM, HDIM / TN);
  for (int e = 0; e < NEXP; e++) {
    const float* w1e = w1 + (size_t)e * DIM * HDIM;
    const float* b1e = b1 + (size_t)e * HDIM;
    const float* w2e = w2 + (size_t)e * HDIM * ODIM;
    const float* b2e = b2 + (size_t)e * ODIM;
    const int* etok_e = etok + (size_t)e * CAPACITY;
    const float* ewt_e = ewt + (size_t)e * CAPACITY;
    const int* cnt_e = list_cnt + e;
    ffn1_kernel<<<gemm_grid, 256, 0, stream>>>(x, w1e, b1e, etok_e, cnt_e, hbuf);
    ffn2_kernel<<<gemm_grid, 256, 0, stream>>>(hbuf, w2e, b2e, etok_e, ewt_e, cnt_e, out);
  }
}

// Round 2
// 1279.861 us; speedup vs baseline: 3.7242x; 3.7242x over previous
//
#include <hip/hip_runtime.h>
#include <math.h>

#define N_TOK 8192
#define DIM 2048
#define HDIM 2048
#define ODIM 2048
#define NEXP 8
#define CAPACITY 2560

typedef __bf16 bf16x8 __attribute__((ext_vector_type(8)));
typedef float f32x4 __attribute__((ext_vector_type(4)));

__device__ __forceinline__ void async16(const void* g, void* l) {
  __builtin_amdgcn_global_load_lds(
      (const __attribute__((address_space(1))) void*)g,
      (__attribute__((address_space(3))) void*)l, 16, 0, 0);
}

// ---------------- router: 1 wave per token ----------------
__global__ __launch_bounds__(64) void router_kernel(
    const float* __restrict__ x, const float* __restrict__ gate_w,
    const float* __restrict__ gate_b, const float* __restrict__ temp,
    float* __restrict__ probs, int* __restrict__ sel, float* __restrict__ rwv) {
  int t = blockIdx.x;
  int lane = threadIdx.x;
  const float* xr = x + (size_t)t * DIM;
  float part[NEXP];
#pragma unroll
  for (int e = 0; e < NEXP; e++) part[e] = 0.f;
  for (int k = lane; k < DIM; k += 64) {
    float xv = xr[k];
    const float* gw = gate_w + (size_t)k * NEXP;
#pragma unroll
    for (int e = 0; e < NEXP; e++) part[e] += xv * gw[e];
  }
#pragma unroll
  for (int e = 0; e < NEXP; e++) {
    float v = part[e];
#pragma unroll
    for (int off = 32; off > 0; off >>= 1) v += __shfl_down(v, off);
    part[e] = v;
  }
  if (lane == 0) {
    float it = 1.0f / fabsf(temp[0]);
    float lg[NEXP];
    float m = -1e30f;
#pragma unroll
    for (int e = 0; e < NEXP; e++) {
      lg[e] = (part[e] + gate_b[e]) * it;
      m = fmaxf(m, lg[e]);
    }
    float s = 0.f;
    float p[NEXP];
#pragma unroll
    for (int e = 0; e < NEXP; e++) { p[e] = expf(lg[e] - m); s += p[e]; }
    float inv_s = 1.f / s;
#pragma unroll
    for (int e = 0; e < NEXP; e++) { p[e] *= inv_s; probs[(size_t)t * NEXP + e] = p[e]; }
    int e1 = 0;
#pragma unroll
    for (int e = 1; e < NEXP; e++) if (p[e] > p[e1]) e1 = e;
    int e2 = -1;
#pragma unroll
    for (int e = 0; e < NEXP; e++) {
      if (e == e1) continue;
      if (e2 < 0 || p[e] > p[e2]) e2 = e;
    }
    float s2 = p[e1] + p[e2];
    sel[t * 2 + 0] = e1;
    sel[t * 2 + 1] = e2;
    rwv[t * 2 + 0] = p[e1] / s2;
    rwv[t * 2 + 1] = p[e2] / s2;
  }
}

// ---------------- aux loss + per-expert assignment counts ----------------
__global__ __launch_bounds__(256) void aux_kernel(
    const float* __restrict__ probs, const int* __restrict__ sel,
    float* __restrict__ aux_out, int* __restrict__ cnt_assign,
    int* __restrict__ list_cnt) {
  int tid = threadIdx.x;
  float lps[NEXP];
  int lc[NEXP];
#pragma unroll
  for (int e = 0; e < NEXP; e++) { lps[e] = 0.f; lc[e] = 0; }
  for (int t = tid; t < N_TOK; t += 256) {
    const float* pr = probs + (size_t)t * NEXP;
#pragma unroll
    for (int e = 0; e < NEXP; e++) lps[e] += pr[e];
  }
  for (int j = tid; j < N_TOK * 2; j += 256) lc[sel[j]]++;
  __shared__ float sps[NEXP][256];
  __shared__ int scs[NEXP][256];
#pragma unroll
  for (int e = 0; e < NEXP; e++) { sps[e][tid] = lps[e]; scs[e][tid] = lc[e]; }
  __syncthreads();
  for (int off = 128; off > 0; off >>= 1) {
    if (tid < off) {
#pragma unroll
      for (int e = 0; e < NEXP; e++) {
        sps[e][tid] += sps[e][tid + off];
        scs[e][tid] += scs[e][tid + off];
      }
    }
    __syncthreads();
  }
  if (tid < NEXP) {
    cnt_assign[tid] = scs[tid][0];
    list_cnt[tid] = 0;
  }
  if (tid == 0) {
    float ps[NEXP];
    int cs[NEXP];
#pragma unroll
    for (int e = 0; e < NEXP; e++) { ps[e] = sps[e][0]; cs[e] = scs[e][0]; }
    float balance = 0.f;
#pragma unroll
    for (int e = 0; e < NEXP; e++)
      balance += (ps[e] / (float)N_TOK) * ((float)cs[e] / (float)N_TOK);
    balance *= (float)NEXP;
    float meanimp = 0.f;
#pragma unroll
    for (int e = 0; e < NEXP; e++) meanimp += ps[e];
    meanimp /= (float)NEXP;
    float var = 0.f;
#pragma unroll
    for (int e = 0; e < NEXP; e++) { float d = ps[e] - meanimp; var += d * d; }
    var /= (float)(NEXP - 1);
    float cv = sqrtf(var) / (meanimp + 1e-10f);
    aux_out[0] = balance + 0.01f * cv;
  }
}

// ---------------- out = x (residual init) ----------------
__global__ __launch_bounds__(256) void copy_kernel(const float4* __restrict__ src,
                                                   float4* __restrict__ dst, int n4) {
  int i = blockIdx.x * blockDim.x + threadIdx.x;
  int stride = gridDim.x * blockDim.x;
  for (; i < n4; i += stride) dst[i] = src[i];
}

// ---------------- x -> bf16 ----------------
__global__ __launch_bounds__(256) void cvt_x_kernel(const float4* __restrict__ src,
                                                    ushort* __restrict__ dst, int n4) {
  int i = blockIdx.x * blockDim.x + threadIdx.x;
  int stride = gridDim.x * blockDim.x;
  for (; i < n4; i += stride) {
    float4 v = src[i];
    __bf16 o[4] = {(__bf16)v.x, (__bf16)v.y, (__bf16)v.z, (__bf16)v.w};
    *(ushort4*)(dst + (size_t)i * 4) = *(const ushort4*)o;
  }
}

// ---------------- weight transpose + convert: [K][N] f32 -> [N][K] bf16 ----
// grid (32, 32, 16): 64x64 tiles, z selects matrix (0..7 w1, 8..15 w2)
__global__ __launch_bounds__(256) void transpose_cvt_kernel(
    const float* __restrict__ w1, const float* __restrict__ w2,
    ushort* __restrict__ wt_all) {
  int z = blockIdx.z;
  const float* src = (z < 8) ? (w1 + (size_t)z * DIM * HDIM)
                             : (w2 + (size_t)(z - 8) * HDIM * ODIM);
  ushort* dst = wt_all + (size_t)z * 2048 * 2048;
  __shared__ float tile[64][68];
  int tid = threadIdx.x;
  int k0 = blockIdx.x * 64;
  int n0 = blockIdx.y * 64;
  int tr = tid >> 4;          // 0..15
  int tc = (tid & 15) * 4;    // 0..60
#pragma unroll
  for (int i = 0; i < 4; i++) {
    int r = tr + i * 16;
    float4 v = *(const float4*)(src + (size_t)(k0 + r) * 2048 + n0 + tc);
    *(float4*)&tile[r][tc] = v;
  }
  __syncthreads();
#pragma unroll
  for (int i = 0; i < 4; i++) {
    int n = tr + i * 16;  // local n
    __bf16 o[4];
#pragma unroll
    for (int j = 0; j < 4; j++) o[j] = (__bf16)tile[tc + j][n];
    *(ushort4*)(dst + (size_t)(n0 + n) * 2048 + k0 + tc) = *(const ushort4*)o;
  }
}

// ---------------- capacity-exact expert list build ----------------
__global__ __launch_bounds__(256) void build_lists(
    const int* __restrict__ sel, const float* __restrict__ rwv,
    const int* __restrict__ cnt_assign, int* __restrict__ list_cnt,
    int* __restrict__ etok, float* __restrict__ ewt) {
  int j = blockIdx.x * blockDim.x + threadIdx.x;
  if (j >= N_TOK * 2) return;
  int e = sel[j];
  float w = rwv[j];
  bool keep = true;
  if (cnt_assign[e] > CAPACITY) {
    int rank = 0;
    for (int j2 = 0; j2 < N_TOK * 2; j2++) {
      if (sel[j2] == e) {
        float w2 = rwv[j2];
        if (w2 > w || (w2 == w && j2 < j)) rank++;
      }
    }
    keep = (rank < CAPACITY);
  }
  if (keep) {
    int slot = atomicAdd(&list_cnt[e], 1);
    etok[(size_t)e * CAPACITY + slot] = j >> 1;
    ewt[(size_t)e * CAPACITY + slot] = w;
  }
}

// ---------------- MFMA FFN1: h = relu(Xg @ w1 + b1), bf16 out ----------------
// grid (20, 16, 8), 256 threads. Tile 128x128, BK=32.
__global__ __launch_bounds__(256) void mfma_ffn1(
    const __bf16* __restrict__ xb, const __bf16* __restrict__ w1t,
    const float* __restrict__ b1, const int* __restrict__ etok,
    const int* __restrict__ list_cnt, __bf16* __restrict__ h) {
  int e = blockIdx.z;
  int cnt = list_cnt[e];
  int row0 = blockIdx.x * 128;
  if (row0 >= cnt) return;
  int col0 = blockIdx.y * 128;
  const __bf16* wte = w1t + (size_t)e * DIM * HDIM;  // [H][D] bf16
  const int* etok_e = etok + e * CAPACITY;
  const float* b1e = b1 + (size_t)e * HDIM;
  __bf16* hexp = h + (size_t)e * CAPACITY * HDIM;

  __shared__ __bf16 Asm[4 * 128 * 8];  // [chunk][row][8]
  __shared__ __bf16 Bsm[4 * 128 * 8];

  int tid = threadIdx.x;
  int r = tid & 127;
  int chi = tid >> 7;  // 0/1 -> chunks chi, chi+2
  int row_idx = row0 + r;
  int tok = (row_idx < cnt) ? etok_e[row_idx] : 0;
  const __bf16* ga = xb + (size_t)tok * DIM;
  const __bf16* gb = wte + (size_t)(col0 + r) * DIM;

  int wv = tid >> 6, lane = tid & 63;
  int wrow = (wv & 1) * 64, wcol = (wv >> 1) * 64;
  int lm = lane & 15, lg = lane >> 4;

  const __bf16* Abase = &Asm[(size_t)(lg * 128 + wrow + lm) * 8];
  const __bf16* Bbase = &Bsm[(size_t)(lg * 128 + wcol + lm) * 8];

  f32x4 acc[4][4] = {};

  for (int k0 = 0; k0 < DIM; k0 += 32) {
    __syncthreads();
    int c0 = chi, c1 = chi + 2;
    async16(ga + k0 + c0 * 8, &Asm[(size_t)(c0 * 128 + r) * 8]);
    async16(ga + k0 + c1 * 8, &Asm[(size_t)(c1 * 128 + r) * 8]);
    async16(gb + k0 + c0 * 8, &Bsm[(size_t)(c0 * 128 + r) * 8]);
    async16(gb + k0 + c1 * 8, &Bsm[(size_t)(c1 * 128 + r) * 8]);
    __syncthreads();
    bf16x8 af[4], bfr[4];
#pragma unroll
    for (int mt = 0; mt < 4; mt++) af[mt] = *(const bf16x8*)(Abase + mt * 16 * 8);
#pragma unroll
    for (int nt = 0; nt < 4; nt++) bfr[nt] = *(const bf16x8*)(Bbase + nt * 16 * 8);
#pragma unroll
    for (int mt = 0; mt < 4; mt++)
#pragma unroll
      for (int nt = 0; nt < 4; nt++)
        acc[mt][nt] = __builtin_amdgcn_mfma_f32_16x16x32_bf16(af[mt], bfr[nt],
                                                              acc[mt][nt], 0, 0, 0);
  }
  // epilogue: C layout col=lane&15, row=(lane>>4)*4+reg
#pragma unroll
  for (int nt = 0; nt < 4; nt++) {
    int colg = col0 + wcol + nt * 16 + lm;
    float bias = b1e[colg];
#pragma unroll
    for (int mt = 0; mt < 4; mt++) {
#pragma unroll
      for (int reg = 0; reg < 4; reg++) {
        int rowg = row0 + wrow + mt * 16 + lg * 4 + reg;
        float v = acc[mt][nt][reg] + bias;
        hexp[(size_t)rowg * HDIM + colg] = (__bf16)fmaxf(v, 0.f);
      }
    }
  }
}

// ---------------- MFMA FFN2: out[tok] += (h @ w2 + b2) * wt ----------------
__global__ __launch_bounds__(256) void mfma_ffn2(
    const __bf16* __restrict__ h, const __bf16* __restrict__ w2t,
    const float* __restrict__ b2, const int* __restrict__ etok,
    const float* __restrict__ ewt, const int* __restrict__ list_cnt,
    float* __restrict__ out) {
  int e = blockIdx.z;
  int cnt = list_cnt[e];
  int row0 = blockIdx.x * 128;
  if (row0 >= cnt) return;
  int col0 = blockIdx.y * 128;
  const __bf16* wte = w2t + (size_t)e * HDIM * ODIM;  // [O][H] bf16
  const __bf16* hexp = h + (size_t)e * CAPACITY * HDIM;
  const int* etok_e = etok + e * CAPACITY;
  const float* ewt_e = ewt + e * CAPACITY;
  const float* b2e = b2 + (size_t)e * ODIM;

  __shared__ __bf16 Asm[4 * 128 * 8];
  __shared__ __bf16 Bsm[4 * 128 * 8];

  int tid = threadIdx.x;
  int r = tid & 127;
  int chi = tid >> 7;
  const __bf16* ga = hexp + (size_t)(row0 + r) * HDIM;
  const __bf16* gb = wte + (size_t)(col0 + r) * HDIM;

  int wv = tid >> 6, lane = tid & 63;
  int wrow = (wv & 1) * 64, wcol = (wv >> 1) * 64;
  int lm = lane & 15, lg = lane >> 4;

  const __bf16* Abase = &Asm[(size_t)(lg * 128 + wrow + lm) * 8];
  const __bf16* Bbase = &Bsm[(size_t)(lg * 128 + wcol + lm) * 8];

  f32x4 acc[4][4] = {};

  for (int k0 = 0; k0 < HDIM; k0 += 32) {
    __syncthreads();
    int c0 = chi, c1 = chi + 2;
    async16(ga + k0 + c0 * 8, &Asm[(size_t)(c0 * 128 + r) * 8]);
    async16(ga + k0 + c1 * 8, &Asm[(size_t)(c1 * 128 + r) * 8]);
    async16(gb + k0 + c0 * 8, &Bsm[(size_t)(c0 * 128 + r) * 8]);
    async16(gb + k0 + c1 * 8, &Bsm[(size_t)(c1 * 128 + r) * 8]);
    __syncthreads();
    bf16x8 af[4], bfr[4];
#pragma unroll
    for (int mt = 0; mt < 4; mt++) af[mt] = *(const bf16x8*)(Abase + mt * 16 * 8);
#pragma unroll
    for (int nt = 0; nt < 4; nt++) bfr[nt] = *(const bf16x8*)(Bbase + nt * 16 * 8);
#pragma unroll
    for (int mt = 0; mt < 4; mt++)
#pragma unroll
      for (int nt = 0; nt < 4; nt++)
        acc[mt][nt] = __builtin_amdgcn_mfma_f32_16x16x32_bf16(af[mt], bfr[nt],
                                                              acc[mt][nt], 0, 0, 0);
  }
#pragma unroll
  for (int mt = 0; mt < 4; mt++) {
#pragma unroll
    for (int reg = 0; reg < 4; reg++) {
      int rowg = row0 + wrow + mt * 16 + lg * 4 + reg;
      if (rowg < cnt) {
        int tok = etok_e[rowg];
        float wt = ewt_e[rowg];
        float* orow = out + (size_t)tok * ODIM;
#pragma unroll
        for (int nt = 0; nt < 4; nt++) {
          int colg = col0 + wcol + nt * 16 + lm;
          atomicAdd(&orow[colg], (acc[mt][nt][reg] + b2e[colg]) * wt);
        }
      }
    }
  }
}

extern "C" void kernel_launch(void* const* d_in, const int* in_sizes, int n_in,
                              void* d_out, int out_size, void* d_ws, size_t ws_size,
                              hipStream_t stream) {
  const float* x = (const float*)d_in[0];
  const float* gate_w = (const float*)d_in[1];
  const float* gate_b = (const float*)d_in[2];
  const float* temp = (const float*)d_in[3];
  const float* w1 = (const float*)d_in[4];
  const float* b1 = (const float*)d_in[5];
  const float* w2 = (const float*)d_in[6];
  const float* b2 = (const float*)d_in[7];
  float* out = (float*)d_out;

  char* ws = (char*)d_ws;
  size_t off = 0;
  float* probs = (float*)(ws + off); off += (size_t)N_TOK * NEXP * 4;
  int* sel = (int*)(ws + off);       off += (size_t)N_TOK * 2 * 4;
  float* rwv = (float*)(ws + off);   off += (size_t)N_TOK * 2 * 4;
  int* cnt_assign = (int*)(ws + off); off += 64;
  int* list_cnt = (int*)(ws + off);   off += 64;
  int* etok = (int*)(ws + off);      off += (size_t)NEXP * CAPACITY * 4;
  float* ewt = (float*)(ws + off);   off += (size_t)NEXP * CAPACITY * 4;
  off = (off + 255) & ~(size_t)255;
  ushort* xb = (ushort*)(ws + off);    off += (size_t)N_TOK * DIM * 2;          // 33.5 MB
  ushort* wt_all = (ushort*)(ws + off); off += (size_t)16 * 2048 * 2048 * 2;    // 134 MB
  ushort* hbuf = (ushort*)(ws + off);  off += (size_t)NEXP * CAPACITY * HDIM * 2; // 84 MB

  router_kernel<<<N_TOK, 64, 0, stream>>>(x, gate_w, gate_b, temp, probs, sel, rwv);
  float* aux_out = out + (size_t)N_TOK * ODIM;
  aux_kernel<<<1, 256, 0, stream>>>(probs, sel, aux_out, cnt_assign, list_cnt);
  int n4 = (N_TOK * ODIM) / 4;
  copy_kernel<<<4096, 256, 0, stream>>>((const float4*)x, (float4*)out, n4);
  cvt_x_kernel<<<4096, 256, 0, stream>>>((const float4*)x, xb, (N_TOK * DIM) / 4);
  dim3 tgrid(32, 32, 16);
  transpose_cvt_kernel<<<tgrid, 256, 0, stream>>>(w1, w2, wt_all);
  build_lists<<<(N_TOK * 2 + 255) / 256, 256, 0, stream>>>(sel, rwv, cnt_assign,
                                                           list_cnt, etok, ewt);
  const __bf16* w1t = (const __bf16*)wt_all;
  const __bf16* w2t = (const __bf16*)(wt_all + (size_t)8 * 2048 * 2048);
  dim3 ggrid(CAPACITY / 128, 2048 / 128, NEXP);
  mfma_ffn1<<<ggrid, 256, 0, stream>>>((const __bf16*)xb, w1t, b1, etok, list_cnt,
                                       (__bf16*)hbuf);
  mfma_ffn2<<<ggrid, 256, 0, stream>>>((const __bf16*)hbuf, w2t, b2, etok, ewt,
                                       list_cnt, out);
}

// Round 3
// 1198.957 us; speedup vs baseline: 3.9755x; 1.0675x over previous
//
#include <hip/hip_runtime.h>
#include <math.h>

#define N_TOK 8192
#define DIM 2048
#define HDIM 2048
#define ODIM 2048
#define NEXP 8
#define CAPACITY 2560

typedef __bf16 bf16x8 __attribute__((ext_vector_type(8)));
typedef float f32x4 __attribute__((ext_vector_type(4)));

__device__ __forceinline__ void async16(const void* g, void* l) {
  __builtin_amdgcn_global_load_lds(
      (const __attribute__((address_space(1))) void*)g,
      (__attribute__((address_space(3))) void*)l, 16, 0, 0);
}

// ---------------- router: 1 wave per token; also emits x as bf16 ----------
__global__ __launch_bounds__(64) void router_kernel(
    const float* __restrict__ x, const float* __restrict__ gate_w,
    const float* __restrict__ gate_b, const float* __restrict__ temp,
    float* __restrict__ probs, int* __restrict__ sel, float* __restrict__ rwv,
    __bf16* __restrict__ xb) {
  int t = blockIdx.x;
  int lane = threadIdx.x;
  const float* xr = x + (size_t)t * DIM;
  __bf16* xbr = xb + (size_t)t * DIM;
  float part[NEXP];
#pragma unroll
  for (int e = 0; e < NEXP; e++) part[e] = 0.f;
  for (int k = lane; k < DIM; k += 64) {
    float xv = xr[k];
    xbr[k] = (__bf16)xv;
    const float* gw = gate_w + (size_t)k * NEXP;
#pragma unroll
    for (int e = 0; e < NEXP; e++) part[e] += xv * gw[e];
  }
#pragma unroll
  for (int e = 0; e < NEXP; e++) {
    float v = part[e];
#pragma unroll
    for (int off = 32; off > 0; off >>= 1) v += __shfl_down(v, off);
    part[e] = v;
  }
  if (lane == 0) {
    float it = 1.0f / fabsf(temp[0]);
    float lg[NEXP];
    float m = -1e30f;
#pragma unroll
    for (int e = 0; e < NEXP; e++) {
      lg[e] = (part[e] + gate_b[e]) * it;
      m = fmaxf(m, lg[e]);
    }
    float s = 0.f;
    float p[NEXP];
#pragma unroll
    for (int e = 0; e < NEXP; e++) { p[e] = expf(lg[e] - m); s += p[e]; }
    float inv_s = 1.f / s;
#pragma unroll
    for (int e = 0; e < NEXP; e++) { p[e] *= inv_s; probs[(size_t)t * NEXP + e] = p[e]; }
    int e1 = 0;
#pragma unroll
    for (int e = 1; e < NEXP; e++) if (p[e] > p[e1]) e1 = e;
    int e2 = -1;
#pragma unroll
    for (int e = 0; e < NEXP; e++) {
      if (e == e1) continue;
      if (e2 < 0 || p[e] > p[e2]) e2 = e;
    }
    float s2 = p[e1] + p[e2];
    sel[t * 2 + 0] = e1;
    sel[t * 2 + 1] = e2;
    rwv[t * 2 + 0] = p[e1] / s2;
    rwv[t * 2 + 1] = p[e2] / s2;
  }
}

// ---------------- aux loss + per-expert assignment counts ----------------
__global__ __launch_bounds__(256) void aux_kernel(
    const float* __restrict__ probs, const int* __restrict__ sel,
    float* __restrict__ aux_out, int* __restrict__ cnt_assign,
    int* __restrict__ list_cnt) {
  int tid = threadIdx.x;
  float lps[NEXP];
  int lc[NEXP];
#pragma unroll
  for (int e = 0; e < NEXP; e++) { lps[e] = 0.f; lc[e] = 0; }
  for (int t = tid; t < N_TOK; t += 256) {
    const float* pr = probs + (size_t)t * NEXP;
#pragma unroll
    for (int e = 0; e < NEXP; e++) lps[e] += pr[e];
  }
  for (int j = tid; j < N_TOK * 2; j += 256) lc[sel[j]]++;
  __shared__ float sps[NEXP][256];
  __shared__ int scs[NEXP][256];
#pragma unroll
  for (int e = 0; e < NEXP; e++) { sps[e][tid] = lps[e]; scs[e][tid] = lc[e]; }
  __syncthreads();
  for (int off = 128; off > 0; off >>= 1) {
    if (tid < off) {
#pragma unroll
      for (int e = 0; e < NEXP; e++) {
        sps[e][tid] += sps[e][tid + off];
        scs[e][tid] += scs[e][tid + off];
      }
    }
    __syncthreads();
  }
  if (tid < NEXP) {
    cnt_assign[tid] = scs[tid][0];
    list_cnt[tid] = 0;
  }
  if (tid == 0) {
    float ps[NEXP];
    int cs[NEXP];
#pragma unroll
    for (int e = 0; e < NEXP; e++) { ps[e] = sps[e][0]; cs[e] = scs[e][0]; }
    float balance = 0.f;
#pragma unroll
    for (int e = 0; e < NEXP; e++)
      balance += (ps[e] / (float)N_TOK) * ((float)cs[e] / (float)N_TOK);
    balance *= (float)NEXP;
    float meanimp = 0.f;
#pragma unroll
    for (int e = 0; e < NEXP; e++) meanimp += ps[e];
    meanimp /= (float)NEXP;
    float var = 0.f;
#pragma unroll
    for (int e = 0; e < NEXP; e++) { float d = ps[e] - meanimp; var += d * d; }
    var /= (float)(NEXP - 1);
    float cv = sqrtf(var) / (meanimp + 1e-10f);
    aux_out[0] = balance + 0.01f * cv;
  }
}

// ---------------- weight transpose + convert: [K][N] f32 -> [N][K] bf16 ----
__global__ __launch_bounds__(256) void transpose_cvt_kernel(
    const float* __restrict__ w1, const float* __restrict__ w2,
    ushort* __restrict__ wt_all) {
  int z = blockIdx.z;
  const float* src = (z < 8) ? (w1 + (size_t)z * DIM * HDIM)
                             : (w2 + (size_t)(z - 8) * HDIM * ODIM);
  ushort* dst = wt_all + (size_t)z * 2048 * 2048;
  __shared__ float tile[64][68];
  int tid = threadIdx.x;
  int k0 = blockIdx.x * 64;
  int n0 = blockIdx.y * 64;
  int tr = tid >> 4;
  int tc = (tid & 15) * 4;
#pragma unroll
  for (int i = 0; i < 4; i++) {
    int r = tr + i * 16;
    float4 v = *(const float4*)(src + (size_t)(k0 + r) * 2048 + n0 + tc);
    *(float4*)&tile[r][tc] = v;
  }
  __syncthreads();
#pragma unroll
  for (int i = 0; i < 4; i++) {
    int n = tr + i * 16;
    __bf16 o[4];
#pragma unroll
    for (int j = 0; j < 4; j++) o[j] = (__bf16)tile[tc + j][n];
    *(ushort4*)(dst + (size_t)(n0 + n) * 2048 + k0 + tc) = *(const ushort4*)o;
  }
}

// ---------------- capacity-exact expert list build ----------------
__global__ __launch_bounds__(256) void build_lists(
    const int* __restrict__ sel, const float* __restrict__ rwv,
    const int* __restrict__ cnt_assign, int* __restrict__ list_cnt,
    int* __restrict__ etok, int* __restrict__ pos) {
  int j = blockIdx.x * blockDim.x + threadIdx.x;
  if (j >= N_TOK * 2) return;
  int e = sel[j];
  float w = rwv[j];
  bool keep = true;
  if (cnt_assign[e] > CAPACITY) {
    int rank = 0;
    for (int j2 = 0; j2 < N_TOK * 2; j2++) {
      if (sel[j2] == e) {
        float w2 = rwv[j2];
        if (w2 > w || (w2 == w && j2 < j)) rank++;
      }
    }
    keep = (rank < CAPACITY);
  }
  if (keep) {
    int slot = atomicAdd(&list_cnt[e], 1);
    etok[(size_t)e * CAPACITY + slot] = j >> 1;
    pos[j] = e * CAPACITY + slot;
  } else {
    pos[j] = -1;
  }
}

// ---------------- MFMA FFN1: h = relu(Xg @ w1 + b1), bf16 out ----------------
// grid (20, 16, 8), 256 threads. Tile 128x128, BK=64.
__global__ __launch_bounds__(256) void mfma_ffn1(
    const __bf16* __restrict__ xb, const __bf16* __restrict__ w1t,
    const float* __restrict__ b1, const int* __restrict__ etok,
    const int* __restrict__ list_cnt, __bf16* __restrict__ h) {
  int e = blockIdx.z;
  int cnt = list_cnt[e];
  int row0 = blockIdx.x * 128;
  if (row0 >= cnt) return;
  int col0 = blockIdx.y * 128;
  const __bf16* wte = w1t + (size_t)e * DIM * HDIM;
  const int* etok_e = etok + e * CAPACITY;
  const float* b1e = b1 + (size_t)e * HDIM;
  __bf16* hexp = h + (size_t)e * CAPACITY * HDIM;

  __shared__ __align__(16) char smem[34816];  // staging 32KB; epilogue 128x136 bf16
  __bf16* As = (__bf16*)smem;            // [8 chunks][128][8]
  __bf16* Bs = (__bf16*)(smem + 16384);

  int tid = threadIdx.x;
  int r = tid & 127;
  int chi = tid >> 7;  // chunks chi, chi+2, chi+4, chi+6
  int row_idx = row0 + r;
  int tok = (row_idx < cnt) ? etok_e[row_idx] : 0;
  const __bf16* ga = xb + (size_t)tok * DIM;
  const __bf16* gb = wte + (size_t)(col0 + r) * DIM;

  int wv = tid >> 6, lane = tid & 63;
  int wrow = (wv & 1) * 64, wcol = (wv >> 1) * 64;
  int lm = lane & 15, lg = lane >> 4;

  f32x4 acc[4][4] = {};

  for (int k0 = 0; k0 < DIM; k0 += 64) {
    __syncthreads();
#pragma unroll
    for (int c = 0; c < 4; c++) {
      int ch = chi + c * 2;
      async16(ga + k0 + ch * 8, As + ((size_t)ch * 128 + r) * 8);
      async16(gb + k0 + ch * 8, Bs + ((size_t)ch * 128 + r) * 8);
    }
    __syncthreads();
#pragma unroll
    for (int half = 0; half < 2; half++) {
      const __bf16* Ab = As + ((size_t)((half * 4 + lg) * 128 + wrow + lm)) * 8;
      const __bf16* Bb = Bs + ((size_t)((half * 4 + lg) * 128 + wcol + lm)) * 8;
      bf16x8 af[4], bfr[4];
#pragma unroll
      for (int mt = 0; mt < 4; mt++) af[mt] = *(const bf16x8*)(Ab + mt * 16 * 8);
#pragma unroll
      for (int nt = 0; nt < 4; nt++) bfr[nt] = *(const bf16x8*)(Bb + nt * 16 * 8);
#pragma unroll
      for (int mt = 0; mt < 4; mt++)
#pragma unroll
        for (int nt = 0; nt < 4; nt++)
          acc[mt][nt] = __builtin_amdgcn_mfma_f32_16x16x32_bf16(af[mt], bfr[nt],
                                                                acc[mt][nt], 0, 0, 0);
    }
  }
  // epilogue: transpose through LDS, vector bf16 stores
  __syncthreads();
  __bf16* T = (__bf16*)smem;  // 128 x 136
#pragma unroll
  for (int nt = 0; nt < 4; nt++) {
    int col = wcol + nt * 16 + lm;
    float bias = b1e[col0 + col];
#pragma unroll
    for (int mt = 0; mt < 4; mt++) {
#pragma unroll
      for (int reg = 0; reg < 4; reg++) {
        int row = wrow + mt * 16 + lg * 4 + reg;
        T[row * 136 + col] = (__bf16)fmaxf(acc[mt][nt][reg] + bias, 0.f);
      }
    }
  }
  __syncthreads();
  int rr = tid >> 1, cs = (tid & 1) * 64;
  const __bf16* srcp = T + rr * 136 + cs;
  __bf16* dstp = hexp + (size_t)(row0 + rr) * HDIM + col0 + cs;
#pragma unroll
  for (int i = 0; i < 8; i++)
    *(bf16x8*)(dstp + i * 8) = *(const bf16x8*)(srcp + i * 8);
}

// ---------------- MFMA FFN2: y[e][row] = h @ w2 + b2 (bf16) ----------------
__global__ __launch_bounds__(256) void mfma_ffn2(
    const __bf16* __restrict__ h, const __bf16* __restrict__ w2t,
    const float* __restrict__ b2, const int* __restrict__ list_cnt,
    __bf16* __restrict__ ybuf) {
  int e = blockIdx.z;
  int cnt = list_cnt[e];
  int row0 = blockIdx.x * 128;
  if (row0 >= cnt) return;
  int col0 = blockIdx.y * 128;
  const __bf16* wte = w2t + (size_t)e * HDIM * ODIM;
  const __bf16* hexp = h + (size_t)e * CAPACITY * HDIM;
  const float* b2e = b2 + (size_t)e * ODIM;
  __bf16* yexp = ybuf + (size_t)e * CAPACITY * ODIM;

  __shared__ __align__(16) char smem[34816];
  __bf16* As = (__bf16*)smem;
  __bf16* Bs = (__bf16*)(smem + 16384);

  int tid = threadIdx.x;
  int r = tid & 127;
  int chi = tid >> 7;
  const __bf16* ga = hexp + (size_t)(row0 + r) * HDIM;
  const __bf16* gb = wte + (size_t)(col0 + r) * HDIM;

  int wv = tid >> 6, lane = tid & 63;
  int wrow = (wv & 1) * 64, wcol = (wv >> 1) * 64;
  int lm = lane & 15, lg = lane >> 4;

  f32x4 acc[4][4] = {};

  for (int k0 = 0; k0 < HDIM; k0 += 64) {
    __syncthreads();
#pragma unroll
    for (int c = 0; c < 4; c++) {
      int ch = chi + c * 2;
      async16(ga + k0 + ch * 8, As + ((size_t)ch * 128 + r) * 8);
      async16(gb + k0 + ch * 8, Bs + ((size_t)ch * 128 + r) * 8);
    }
    __syncthreads();
#pragma unroll
    for (int half = 0; half < 2; half++) {
      const __bf16* Ab = As + ((size_t)((half * 4 + lg) * 128 + wrow + lm)) * 8;
      const __bf16* Bb = Bs + ((size_t)((half * 4 + lg) * 128 + wcol + lm)) * 8;
      bf16x8 af[4], bfr[4];
#pragma unroll
      for (int mt = 0; mt < 4; mt++) af[mt] = *(const bf16x8*)(Ab + mt * 16 * 8);
#pragma unroll
      for (int nt = 0; nt < 4; nt++) bfr[nt] = *(const bf16x8*)(Bb + nt * 16 * 8);
#pragma unroll
      for (int mt = 0; mt < 4; mt++)
#pragma unroll
        for (int nt = 0; nt < 4; nt++)
          acc[mt][nt] = __builtin_amdgcn_mfma_f32_16x16x32_bf16(af[mt], bfr[nt],
                                                                acc[mt][nt], 0, 0, 0);
    }
  }
  __syncthreads();
  __bf16* T = (__bf16*)smem;
#pragma unroll
  for (int nt = 0; nt < 4; nt++) {
    int col = wcol + nt * 16 + lm;
    float bias = b2e[col0 + col];
#pragma unroll
    for (int mt = 0; mt < 4; mt++) {
#pragma unroll
      for (int reg = 0; reg < 4; reg++) {
        int row = wrow + mt * 16 + lg * 4 + reg;
        T[row * 136 + col] = (__bf16)(acc[mt][nt][reg] + bias);
      }
    }
  }
  __syncthreads();
  int rr = tid >> 1, cs = (tid & 1) * 64;
  const __bf16* srcp = T + rr * 136 + cs;
  __bf16* dstp = yexp + (size_t)(row0 + rr) * ODIM + col0 + cs;
#pragma unroll
  for (int i = 0; i < 8; i++)
    *(bf16x8*)(dstp + i * 8) = *(const bf16x8*)(srcp + i * 8);
}

// ---------------- combine: out[t] = x[t] + sum_k w_k * y[pos_k] ----------------
__global__ __launch_bounds__(256) void combine_kernel(
    const float* __restrict__ x, const __bf16* __restrict__ ybuf,
    const int* __restrict__ pos, const float* __restrict__ rwv,
    float* __restrict__ out) {
  int t = blockIdx.x;
  int tid = threadIdx.x;
  int c = tid * 8;
  int p0 = pos[t * 2 + 0], p1 = pos[t * 2 + 1];
  float w0 = rwv[t * 2 + 0], w1 = rwv[t * 2 + 1];
  const float* xr = x + (size_t)t * DIM + c;
  float4 v0 = *(const float4*)(xr);
  float4 v1 = *(const float4*)(xr + 4);
  float o[8] = {v0.x, v0.y, v0.z, v0.w, v1.x, v1.y, v1.z, v1.w};
  if (p0 >= 0) {
    bf16x8 y = *(const bf16x8*)(ybuf + (size_t)p0 * ODIM + c);
#pragma unroll
    for (int i = 0; i < 8; i++) o[i] += w0 * (float)y[i];
  }
  if (p1 >= 0) {
    bf16x8 y = *(const bf16x8*)(ybuf + (size_t)p1 * ODIM + c);
#pragma unroll
    for (int i = 0; i < 8; i++) o[i] += w1 * (float)y[i];
  }
  float* orow = out + (size_t)t * ODIM + c;
  *(float4*)(orow) = make_float4(o[0], o[1], o[2], o[3]);
  *(float4*)(orow + 4) = make_float4(o[4], o[5], o[6], o[7]);
}

extern "C" void kernel_launch(void* const* d_in, const int* in_sizes, int n_in,
                              void* d_out, int out_size, void* d_ws, size_t ws_size,
                              hipStream_t stream) {
  const float* x = (const float*)d_in[0];
  const float* gate_w = (const float*)d_in[1];
  const float* gate_b = (const float*)d_in[2];
  const float* temp = (const float*)d_in[3];
  const float* w1 = (const float*)d_in[4];
  const float* b1 = (const float*)d_in[5];
  const float* w2 = (const float*)d_in[6];
  const float* b2 = (const float*)d_in[7];
  float* out = (float*)d_out;

  char* ws = (char*)d_ws;
  size_t off = 0;
  float* probs = (float*)(ws + off); off += (size_t)N_TOK * NEXP * 4;
  int* sel = (int*)(ws + off);       off += (size_t)N_TOK * 2 * 4;
  float* rwv = (float*)(ws + off);   off += (size_t)N_TOK * 2 * 4;
  int* cnt_assign = (int*)(ws + off); off += 64;
  int* list_cnt = (int*)(ws + off);   off += 64;
  int* etok = (int*)(ws + off);      off += (size_t)NEXP * CAPACITY * 4;
  int* pos = (int*)(ws + off);       off += (size_t)N_TOK * 2 * 4;
  off = (off + 255) & ~(size_t)255;
  __bf16* xb = (__bf16*)(ws + off);   off += (size_t)N_TOK * DIM * 2;            // 33.5 MB
  ushort* wt_all = (ushort*)(ws + off); off += (size_t)16 * 2048 * 2048 * 2;     // 134 MB
  __bf16* hbuf = (__bf16*)(ws + off); off += (size_t)NEXP * CAPACITY * HDIM * 2; // 84 MB
  // ybuf (84 MB) aliases xb (33.5 MB) + w1t (first 67 MB of wt_all) — both dead
  // after ffn1. ffn2 reads only w2t (second half of wt_all) + hbuf.
  __bf16* ybuf = xb;

  router_kernel<<<N_TOK, 64, 0, stream>>>(x, gate_w, gate_b, temp, probs, sel, rwv, xb);
  float* aux_out = out + (size_t)N_TOK * ODIM;
  aux_kernel<<<1, 256, 0, stream>>>(probs, sel, aux_out, cnt_assign, list_cnt);
  dim3 tgrid(32, 32, 16);
  transpose_cvt_kernel<<<tgrid, 256, 0, stream>>>(w1, w2, wt_all);
  build_lists<<<(N_TOK * 2 + 255) / 256, 256, 0, stream>>>(sel, rwv, cnt_assign,
                                                           list_cnt, etok, pos);
  const __bf16* w1t = (const __bf16*)wt_all;
  const __bf16* w2t = (const __bf16*)(wt_all + (size_t)8 * 2048 * 2048);
  dim3 ggrid(CAPACITY / 128, 2048 / 128, NEXP);
  mfma_ffn1<<<ggrid, 256, 0, stream>>>(xb, w1t, b1, etok, list_cnt, hbuf);
  mfma_ffn2<<<ggrid, 256, 0, stream>>>(hbuf, w2t, b2, list_cnt, ybuf);
  combine_kernel<<<N_TOK, 256, 0, stream>>>(x, ybuf, pos, rwv, out);
}